// Round 1
// baseline (8433.540 us; speedup 1.0000x reference)
//
#include <hip/hip_runtime.h>
#include <hip/hip_bf16.h>

typedef __attribute__((ext_vector_type(8))) short short8_t;
typedef __attribute__((ext_vector_type(4))) float floatx4;

#define TSTEPS 256
#define BATCH  256
#define HID    1024

// workspace byte offsets
#define WS_WI    0u          // Wi bf16, 1024*1024*2 = 2 MB
#define WS_WH    2097152u    // Wh bf16, 2 MB
#define WS_HBUF  4194304u    // h double buffer, 2*256*1024*2 = 1 MB
#define WS_FLAGS 5242880u    // 256 u32 group counters (stride 16 words)

static __device__ __forceinline__ unsigned short f2bf(float f) {
    union { float f; unsigned int u; } v; v.f = f;
    unsigned int u = v.u;
    u += 0x7fffu + ((u >> 16) & 1u);   // RNE
    return (unsigned short)(u >> 16);
}

// ---------------- prep: fp32->bf16 weights, init h buffer, zero flags ----------------
__global__ void prep_kernel(const float* __restrict__ Wi, const float* __restrict__ Wh,
                            const float* __restrict__ h0,
                            unsigned short* __restrict__ wi_bf,
                            unsigned short* __restrict__ wh_bf,
                            unsigned short* __restrict__ hbuf,
                            unsigned int* __restrict__ flags) {
    unsigned int idx = blockIdx.x * 256u + threadIdx.x;
    if (idx < 1048576u) {
        wi_bf[idx] = f2bf(Wi[idx]);
    } else if (idx < 2097152u) {
        unsigned int i = idx - 1048576u;
        wh_bf[i] = f2bf(Wh[i]);
    } else if (idx < 2359296u) {
        unsigned int i = idx - 2097152u;
        hbuf[i] = f2bf(h0[i]);          // buffer 0 = initial state
    } else if (idx < 2359552u) {
        flags[idx - 2359296u] = 0u;
    }
}

// ---------------- xi = x @ Wi^T + bi  (M=65536, N=1024, K=1024) ----------------
// 128x128 block tile, 4 waves each 64x64, BK=32, bf16 MFMA.
__global__ __launch_bounds__(256) void xi_gemm(
    const float* __restrict__ X,
    const unsigned short* __restrict__ Wi_bf,
    const float* __restrict__ Wi_b,
    float* __restrict__ Out) {
    __shared__ unsigned short As[128][40];   // pad 32->40 (80B rows, 16B-aligned)
    __shared__ unsigned short Bs[128][40];

    int tid = threadIdx.x;
    int bx = blockIdx.x;
    int bm = bx >> 3, bn = bx & 7;
    int wave = tid >> 6, lane = tid & 63, l15 = lane & 15, quad = lane >> 4;
    int mw = (wave >> 1) * 64, nw = (wave & 1) * 64;

    floatx4 acc[4][4];
#pragma unroll
    for (int i = 0; i < 4; ++i)
#pragma unroll
        for (int j = 0; j < 4; ++j) acc[i][j] = (floatx4){0.f, 0.f, 0.f, 0.f};

    int srow = tid >> 1;            // 0..127
    int shalf = tid & 1;            // which 16-element half of the 32-wide k tile
    const float* ap = X + (long)(bm * 128 + srow) * 1024 + shalf * 16;
    const unsigned short* bp = Wi_bf + (long)(bn * 128 + srow) * 1024 + shalf * 16;
    unsigned short* asw = &As[srow][shalf * 16];
    unsigned short* bsw = &Bs[srow][shalf * 16];

    for (int kt = 0; kt < 32; ++kt) {
        float4 a0 = *(const float4*)(ap + 0);
        float4 a1 = *(const float4*)(ap + 4);
        float4 a2 = *(const float4*)(ap + 8);
        float4 a3 = *(const float4*)(ap + 12);
        short8_t b0 = *(const short8_t*)(bp);
        short8_t b1 = *(const short8_t*)(bp + 8);
        ap += 32; bp += 32;

        short8_t av0, av1;
        av0[0] = (short)f2bf(a0.x); av0[1] = (short)f2bf(a0.y);
        av0[2] = (short)f2bf(a0.z); av0[3] = (short)f2bf(a0.w);
        av0[4] = (short)f2bf(a1.x); av0[5] = (short)f2bf(a1.y);
        av0[6] = (short)f2bf(a1.z); av0[7] = (short)f2bf(a1.w);
        av1[0] = (short)f2bf(a2.x); av1[1] = (short)f2bf(a2.y);
        av1[2] = (short)f2bf(a2.z); av1[3] = (short)f2bf(a2.w);
        av1[4] = (short)f2bf(a3.x); av1[5] = (short)f2bf(a3.y);
        av1[6] = (short)f2bf(a3.z); av1[7] = (short)f2bf(a3.w);

        *(short8_t*)asw = av0;
        *(short8_t*)(asw + 8) = av1;
        *(short8_t*)bsw = b0;
        *(short8_t*)(bsw + 8) = b1;
        __syncthreads();

        short8_t aF[4], bF[4];
#pragma unroll
        for (int i = 0; i < 4; ++i) aF[i] = *(const short8_t*)&As[mw + i * 16 + l15][quad * 8];
#pragma unroll
        for (int i = 0; i < 4; ++i) bF[i] = *(const short8_t*)&Bs[nw + i * 16 + l15][quad * 8];
#pragma unroll
        for (int i = 0; i < 4; ++i)
#pragma unroll
            for (int j = 0; j < 4; ++j)
                acc[i][j] = __builtin_amdgcn_mfma_f32_16x16x32_bf16(aF[i], bF[j], acc[i][j], 0, 0, 0);
        __syncthreads();
    }

    long rowbase = (long)bm * 128 + mw + quad * 4;
    int colbase = bn * 128 + nw + l15;
#pragma unroll
    for (int j = 0; j < 4; ++j) {
        float bias = Wi_b[colbase + j * 16];
#pragma unroll
        for (int i = 0; i < 4; ++i)
#pragma unroll
            for (int r = 0; r < 4; ++r)
                Out[(rowbase + i * 16 + r) * 1024 + colbase + j * 16] = acc[i][j][r] + bias;
    }
}

// ---------------- recurrent scan: h = tanh(xi_t + h @ Wh^T + bh) ----------------
// 16 groups x 16 rows. Group g served by 16 WGs (bx % 16 == g -> XCD-local under
// round-robin dispatch; correctness independent of placement). Each wave owns 16
// columns and keeps its Wh slice resident in 128 VGPRs.
__global__ __launch_bounds__(256) void rnn_scan(
    float* __restrict__ IO,                       // d_out: xi in, h out (in-place)
    const unsigned short* __restrict__ Wh_bf,
    const float* __restrict__ Wh_b,
    unsigned short* __restrict__ hbuf,            // [2][256*1024] bf16
    unsigned int* __restrict__ flags) {
    int bx = blockIdx.x;
    int g = (bx & 7) | (((bx >> 3) & 1) << 3);    // group 0..15 (bx mod 16)
    int j = bx >> 4;                              // column WG 0..15
    int tid = threadIdx.x;
    int wave = tid >> 6, lane = tid & 63, l15 = lane & 15, quad = lane >> 4;
    int row0 = g * 16;
    int col = j * 64 + wave * 16 + l15;

    // resident B fragments: Wh[col][k], k = kt*32 + quad*8 + 0..7
    short8_t bfrag[32];
    const unsigned short* wrow = Wh_bf + (long)col * 1024 + quad * 8;
#pragma unroll
    for (int kt = 0; kt < 32; ++kt) bfrag[kt] = *(const short8_t*)(wrow + kt * 32);

    float bias = Wh_b[col];
    unsigned int aoff = (unsigned int)(row0 + l15) * 1024u + quad * 8u;
    const unsigned int hstride = 256u * 1024u;
    unsigned int* flagp = flags + g * 16;
    unsigned int target = 0;

    for (int t = 0; t < TSTEPS; ++t) {
        const unsigned short* hsrc = hbuf + (t & 1) * hstride + aoff;
        floatx4 acc0 = {0.f, 0.f, 0.f, 0.f};
        floatx4 acc1 = {0.f, 0.f, 0.f, 0.f};
#pragma unroll
        for (int kt = 0; kt < 32; kt += 2) {
            short8_t af0 = *(const short8_t*)(hsrc + kt * 32);
            short8_t af1 = *(const short8_t*)(hsrc + kt * 32 + 32);
            acc0 = __builtin_amdgcn_mfma_f32_16x16x32_bf16(af0, bfrag[kt], acc0, 0, 0, 0);
            acc1 = __builtin_amdgcn_mfma_f32_16x16x32_bf16(af1, bfrag[kt + 1], acc1, 0, 0, 0);
        }
        floatx4 acc = acc0 + acc1;

        long ob = (long)t * (256 * 1024) + (long)(row0 + quad * 4) * 1024 + col;
        unsigned short* hdst = hbuf + ((t + 1) & 1) * hstride + (row0 + quad * 4) * 1024 + col;
#pragma unroll
        for (int r = 0; r < 4; ++r) {
            float z = acc[r] + IO[ob + r * 1024] + bias;
            float hv = tanhf(z);
            IO[ob + r * 1024] = hv;                  // fp32 output
            hdst[r * 1024] = f2bf(hv);               // bf16 state for next step
        }

        // group barrier: syncthreads drains this WG's stores to L2; tid0's
        // release-atomic flushes this WG's L2 before incrementing; consumers
        // acquire-poll (L1/L2 invalidate) before reading the new h strip.
        __syncthreads();
        if (tid == 0)
            __hip_atomic_fetch_add(flagp, 1u, __ATOMIC_RELEASE, __HIP_MEMORY_SCOPE_AGENT);
        target += 16;
        while (__hip_atomic_load(flagp, __ATOMIC_ACQUIRE, __HIP_MEMORY_SCOPE_AGENT) < target)
            __builtin_amdgcn_s_sleep(1);
    }
}

extern "C" void kernel_launch(void* const* d_in, const int* in_sizes, int n_in,
                              void* d_out, int out_size, void* d_ws, size_t ws_size,
                              hipStream_t stream) {
    const float* x    = (const float*)d_in[0];
    const float* h0   = (const float*)d_in[1];
    const float* Wi_w = (const float*)d_in[2];
    const float* Wi_b = (const float*)d_in[3];
    const float* Wh_w = (const float*)d_in[4];
    const float* Wh_b = (const float*)d_in[5];
    float* out = (float*)d_out;
    char* ws = (char*)d_ws;
    unsigned short* wi_bf = (unsigned short*)(ws + WS_WI);
    unsigned short* wh_bf = (unsigned short*)(ws + WS_WH);
    unsigned short* hbuf  = (unsigned short*)(ws + WS_HBUF);
    unsigned int*   flags = (unsigned int*)(ws + WS_FLAGS);

    prep_kernel<<<9217, 256, 0, stream>>>(Wi_w, Wh_w, h0, wi_bf, wh_bf, hbuf, flags);
    xi_gemm<<<4096, 256, 0, stream>>>(x, wi_bf, Wi_b, out);
    rnn_scan<<<256, 256, 0, stream>>>(out, wh_bf, Wh_b, hbuf, flags);
}

// Round 2
// 7462.378 us; speedup vs baseline: 1.1301x; 1.1301x over previous
//
#include <hip/hip_runtime.h>
#include <hip/hip_bf16.h>

typedef __attribute__((ext_vector_type(8))) short short8_t;
typedef __attribute__((ext_vector_type(4))) float floatx4;

#define TSTEPS 256
#define BATCH  256
#define HID    1024

// workspace byte offsets
#define WS_WI  0u          // Wi bf16, 1024*1024*2 = 2 MB
#define WS_WHP 2097152u    // Wh bf16, repacked into MFMA B-fragment order, 2 MB

static __device__ __forceinline__ unsigned short f2bf(float f) {
    union { float f; unsigned int u; } v; v.f = f;
    unsigned int u = v.u;
    u += 0x7fffu + ((u >> 16) & 1u);   // RNE
    return (unsigned short)(u >> 16);
}

// ---------------- prep: Wi fp32->bf16; Wh fp32->bf16 repacked fragment-major ----------------
// Whp flat index: (((colt*32 + kt)*4 + quad)*16 + l15)*8 + e
//   col = colt*16 + l15, k = kt*32 + quad*8 + e
// so each (colt,kt,quad-spread) wave B-fragment read is 1 KB contiguous.
__global__ void prep_kernel(const float* __restrict__ Wi, const float* __restrict__ Wh,
                            unsigned short* __restrict__ wi_bf,
                            unsigned short* __restrict__ whp) {
    unsigned int idx = blockIdx.x * 256u + threadIdx.x;
    if (idx < 1048576u) {
        wi_bf[idx] = f2bf(Wi[idx]);
    } else {
        unsigned int o = idx - 1048576u;
        unsigned int e    = o & 7u;
        unsigned int l15  = (o >> 3) & 15u;
        unsigned int quad = (o >> 7) & 3u;
        unsigned int kt   = (o >> 9) & 31u;
        unsigned int colt = o >> 14;
        unsigned int col = colt * 16u + l15;
        unsigned int k   = kt * 32u + quad * 8u + e;
        whp[o] = f2bf(Wh[col * 1024u + k]);
    }
}

// ---------------- xi = x @ Wi^T + bi  (M=65536, N=1024, K=1024) ---------------- (unchanged)
__global__ __launch_bounds__(256) void xi_gemm(
    const float* __restrict__ X,
    const unsigned short* __restrict__ Wi_bf,
    const float* __restrict__ Wi_b,
    float* __restrict__ Out) {
    __shared__ unsigned short As[128][40];
    __shared__ unsigned short Bs[128][40];

    int tid = threadIdx.x;
    int bx = blockIdx.x;
    int bm = bx >> 3, bn = bx & 7;
    int wave = tid >> 6, lane = tid & 63, l15 = lane & 15, quad = lane >> 4;
    int mw = (wave >> 1) * 64, nw = (wave & 1) * 64;

    floatx4 acc[4][4];
#pragma unroll
    for (int i = 0; i < 4; ++i)
#pragma unroll
        for (int j = 0; j < 4; ++j) acc[i][j] = (floatx4){0.f, 0.f, 0.f, 0.f};

    int srow = tid >> 1;
    int shalf = tid & 1;
    const float* ap = X + (long)(bm * 128 + srow) * 1024 + shalf * 16;
    const unsigned short* bp = Wi_bf + (long)(bn * 128 + srow) * 1024 + shalf * 16;
    unsigned short* asw = &As[srow][shalf * 16];
    unsigned short* bsw = &Bs[srow][shalf * 16];

    for (int kt = 0; kt < 32; ++kt) {
        float4 a0 = *(const float4*)(ap + 0);
        float4 a1 = *(const float4*)(ap + 4);
        float4 a2 = *(const float4*)(ap + 8);
        float4 a3 = *(const float4*)(ap + 12);
        short8_t b0 = *(const short8_t*)(bp);
        short8_t b1 = *(const short8_t*)(bp + 8);
        ap += 32; bp += 32;

        short8_t av0, av1;
        av0[0] = (short)f2bf(a0.x); av0[1] = (short)f2bf(a0.y);
        av0[2] = (short)f2bf(a0.z); av0[3] = (short)f2bf(a0.w);
        av0[4] = (short)f2bf(a1.x); av0[5] = (short)f2bf(a1.y);
        av0[6] = (short)f2bf(a1.z); av0[7] = (short)f2bf(a1.w);
        av1[0] = (short)f2bf(a2.x); av1[1] = (short)f2bf(a2.y);
        av1[2] = (short)f2bf(a2.z); av1[3] = (short)f2bf(a2.w);
        av1[4] = (short)f2bf(a3.x); av1[5] = (short)f2bf(a3.y);
        av1[6] = (short)f2bf(a3.z); av1[7] = (short)f2bf(a3.w);

        *(short8_t*)asw = av0;
        *(short8_t*)(asw + 8) = av1;
        *(short8_t*)bsw = b0;
        *(short8_t*)(bsw + 8) = b1;
        __syncthreads();

        short8_t aF[4], bF[4];
#pragma unroll
        for (int i = 0; i < 4; ++i) aF[i] = *(const short8_t*)&As[mw + i * 16 + l15][quad * 8];
#pragma unroll
        for (int i = 0; i < 4; ++i) bF[i] = *(const short8_t*)&Bs[nw + i * 16 + l15][quad * 8];
#pragma unroll
        for (int i = 0; i < 4; ++i)
#pragma unroll
            for (int j = 0; j < 4; ++j)
                acc[i][j] = __builtin_amdgcn_mfma_f32_16x16x32_bf16(aF[i], bF[j], acc[i][j], 0, 0, 0);
        __syncthreads();
    }

    long rowbase = (long)bm * 128 + mw + quad * 4;
    int colbase = bn * 128 + nw + l15;
#pragma unroll
    for (int j = 0; j < 4; ++j) {
        float bias = Wi_b[colbase + j * 16];
#pragma unroll
        for (int i = 0; i < 4; ++i)
#pragma unroll
            for (int r = 0; r < 4; ++r)
                Out[(rowbase + i * 16 + r) * 1024 + colbase + j * 16] = acc[i][j][r] + bias;
    }
}

// ---------------- recurrent scan: h = tanh(xi_t + h @ Wh^T + bh) ----------------
// One WG (1024 thr = 16 waves) per 16-row batch group -> NO cross-WG sync.
// h double-buffered in LDS (2 x 16 x 1024 bf16 = 64 KB), XOR-swizzled per row
// (keeps ds_read_b128 16B-aligned, <=2-way bank aliasing which is free).
// Each wave owns 64 columns; Wh streamed from L2 in fragment-packed 1KB reads.
__global__ __launch_bounds__(1024) void rnn_scan(
    float* __restrict__ IO,                       // d_out: xi in, h out (in-place)
    const unsigned short* __restrict__ whp,       // fragment-packed Wh bf16
    const float* __restrict__ Wh_b,
    const float* __restrict__ h0) {
    __shared__ __align__(16) char hmem[65536];    // [2][16 rows][1024] bf16, swizzled

    int g = blockIdx.x;                           // batch group 0..15
    int row0 = g * 16;
    int tid = threadIdx.x;
    int wave = tid >> 6, lane = tid & 63, l15 = lane & 15, quad = lane >> 4;

    // ---- stage h0 (fp32 -> bf16) into buffer 0 ----
    {
        int base = tid * 16;                      // 16 elements per thread
        int row = base >> 10;
        int c0 = base & 1023;
        const float* src = h0 + (long)(row0 + row) * 1024 + c0;
        unsigned int sw = (unsigned int)((row & 7) << 4);
        char* dst = hmem + row * 2048;
#pragma unroll
        for (int i = 0; i < 16; ++i) {
            unsigned short v = f2bf(src[i]);
            *(unsigned short*)(dst + (((unsigned int)((c0 + i) * 2)) ^ sw)) = v;
        }
    }

    float bias[4];
    int cols[4];
    const unsigned short* wq[4];
#pragma unroll
    for (int c = 0; c < 4; ++c) {
        int ct = wave * 4 + c;                    // column tile 0..63
        int col = ct * 16 + l15;
        cols[c] = col;
        bias[c] = Wh_b[col];
        // fragment base: ct*16384 + quad*128 + l15*8; per-kt stride 512 elements
        wq[c] = whp + (unsigned int)(ct * 16384 + quad * 128 + l15 * 8);
    }
    __syncthreads();

    unsigned int asw = (unsigned int)((l15 & 7) << 4);
    const char* arow = hmem + l15 * 2048;
    unsigned int q16 = (unsigned int)(quad * 16);

    for (int t = 0; t < TSTEPS; ++t) {
        const char* abase = arow + ((t & 1) << 15);
        floatx4 acc[4][2];
#pragma unroll
        for (int c = 0; c < 4; ++c) {
            acc[c][0] = (floatx4){0.f, 0.f, 0.f, 0.f};
            acc[c][1] = (floatx4){0.f, 0.f, 0.f, 0.f};
        }
#pragma unroll 2
        for (int kt = 0; kt < 32; ++kt) {
            short8_t af = *(const short8_t*)(abase + (((unsigned int)(kt * 64) + q16) ^ asw));
            const int p = kt & 1;                 // even/odd accumulators (bit-identical order)
#pragma unroll
            for (int c = 0; c < 4; ++c) {
                short8_t bf = *(const short8_t*)(wq[c] + (unsigned int)kt * 512u);
                acc[c][p] = __builtin_amdgcn_mfma_f32_16x16x32_bf16(af, bf, acc[c][p], 0, 0, 0);
            }
        }

        long ob = (long)t * (BATCH * HID) + (long)(row0 + quad * 4) * 1024;
        char* wb = hmem + (((t + 1) & 1) << 15);
#pragma unroll
        for (int c = 0; c < 4; ++c) {
            floatx4 a = acc[c][0] + acc[c][1];
            int col = cols[c];
#pragma unroll
            for (int r = 0; r < 4; ++r) {
                long idx = ob + (long)r * 1024 + col;
                float z = a[r] + IO[idx] + bias[c];
                float hv = tanhf(z);
                IO[idx] = hv;                     // fp32 output
                int row = (quad << 2) + r;
                *(unsigned short*)(wb + row * 2048 +
                    (((unsigned int)(col * 2)) ^ (unsigned int)((row & 7) << 4))) = f2bf(hv);
            }
        }
        __syncthreads();                          // one WG-local barrier per step
    }
}

extern "C" void kernel_launch(void* const* d_in, const int* in_sizes, int n_in,
                              void* d_out, int out_size, void* d_ws, size_t ws_size,
                              hipStream_t stream) {
    const float* x    = (const float*)d_in[0];
    const float* h0   = (const float*)d_in[1];
    const float* Wi_w = (const float*)d_in[2];
    const float* Wi_b = (const float*)d_in[3];
    const float* Wh_w = (const float*)d_in[4];
    const float* Wh_b = (const float*)d_in[5];
    float* out = (float*)d_out;
    char* ws = (char*)d_ws;
    unsigned short* wi_bf = (unsigned short*)(ws + WS_WI);
    unsigned short* whp   = (unsigned short*)(ws + WS_WHP);

    prep_kernel<<<8192, 256, 0, stream>>>(Wi_w, Wh_w, wi_bf, whp);
    xi_gemm<<<4096, 256, 0, stream>>>(x, wi_bf, Wi_b, out);
    rnn_scan<<<16, 1024, 0, stream>>>(out, whp, Wh_b, h0);
}